// Round 1
// baseline (276.001 us; speedup 1.0000x reference)
//
#include <hip/hip_runtime.h>
#include <math.h>

// Problem constants
#define NS   32768      // number of vectors (128*16*16)
#define DIMV 256        // embedding dim
#define KC   1024       // codebook size
#define NBLK 8          // code blocks of 128
#define INV_T 100.0f    // 1/temperature

// ws layout (float offsets)
#define X2_OFF   0                         // 32768 floats: ||x||^2
#define C2_OFF   32768                     // 1024 floats: ||c||^2
#define SUMM_OFF 33792                     // [n][8 blocks][4] = 1,048,576 floats
#define HIST_OFF (33792 + 32768*8*4)       // 1024 floats
#define SCAL_OFF (HIST_OFF + 1024)         // [0]=sum_dmin, [1]=sum_sample_entropy
#define IDXI_OFF (SCAL_OFF + 8)            // 32768 ints

// ---------------------------------------------------------------- norms ----
__global__ __launch_bounds__(256) void vq_norms(const float* __restrict__ x,
                                                const float* __restrict__ cb,
                                                float* __restrict__ norms) {
    int wave = threadIdx.x >> 6;
    int lane = threadIdx.x & 63;
    int row  = blockIdx.x * 4 + wave;
    if (row >= NS + KC) return;
    const float* src = (row < NS) ? (x + (size_t)row * DIMV)
                                  : (cb + (size_t)(row - NS) * DIMV);
    float4 v = reinterpret_cast<const float4*>(src)[lane];
    float s = v.x * v.x + v.y * v.y + v.z * v.z + v.w * v.w;
    #pragma unroll
    for (int off = 32; off; off >>= 1) s += __shfl_xor(s, off);
    if (lane == 0) norms[row] = s;   // rows >= NS land at C2_OFF contiguously
}

// ------------------------------------------------ distance GEMM + summaries ----
// grid: (8 code-blocks, 256 sample-blocks), block: 256 threads.
// C-tile 128x128, thread-tile 8 samples x 8 codes (codes split 2x4 at stride 64).
__global__ __launch_bounds__(256, 2) void vq_dist(const float* __restrict__ x,
                                                  const float* __restrict__ cb,
                                                  const float* __restrict__ norms,
                                                  float* __restrict__ summ) {
    __shared__ float As[16][132];   // [d][sample]
    __shared__ float Bs[16][132];   // [d][code]

    const int t  = threadIdx.x;
    const int bx = blockIdx.x;           // code block 0..7
    const int by = blockIdx.y;           // sample block 0..255
    const int sBase = by * 128;
    const int cBase = bx * 128;
    const int tr = t >> 4;               // 0..15 sample group
    const int tc = t & 15;               // 0..15 code group

    float acc[8][8];
    #pragma unroll
    for (int i = 0; i < 8; ++i)
        #pragma unroll
        for (int j = 0; j < 8; ++j) acc[i][j] = 0.f;

    for (int kc = 0; kc < DIMV; kc += 16) {
        __syncthreads();
        #pragma unroll
        for (int h = 0; h < 2; ++h) {
            int v  = t + h * 256;        // 0..511
            int sl = v >> 2;             // 0..127
            int dv = v & 3;              // float4 index within 16-d chunk
            float4 a = *reinterpret_cast<const float4*>(
                &x[(size_t)(sBase + sl) * DIMV + kc + dv * 4]);
            As[dv*4+0][sl] = a.x; As[dv*4+1][sl] = a.y;
            As[dv*4+2][sl] = a.z; As[dv*4+3][sl] = a.w;
            float4 b = *reinterpret_cast<const float4*>(
                &cb[(size_t)(cBase + sl) * DIMV + kc + dv * 4]);
            Bs[dv*4+0][sl] = b.x; Bs[dv*4+1][sl] = b.y;
            Bs[dv*4+2][sl] = b.z; Bs[dv*4+3][sl] = b.w;
        }
        __syncthreads();
        #pragma unroll
        for (int d = 0; d < 16; ++d) {
            float4 a0 = *reinterpret_cast<const float4*>(&As[d][tr * 8]);
            float4 a1 = *reinterpret_cast<const float4*>(&As[d][tr * 8 + 4]);
            float4 b0 = *reinterpret_cast<const float4*>(&Bs[d][tc * 4]);
            float4 b1 = *reinterpret_cast<const float4*>(&Bs[d][64 + tc * 4]);
            float av[8] = {a0.x, a0.y, a0.z, a0.w, a1.x, a1.y, a1.z, a1.w};
            float bv[8] = {b0.x, b0.y, b0.z, b0.w, b1.x, b1.y, b1.z, b1.w};
            #pragma unroll
            for (int i = 0; i < 8; ++i)
                #pragma unroll
                for (int j = 0; j < 8; ++j)
                    acc[i][j] = fmaf(av[i], bv[j], acc[i][j]);
        }
    }

    // Epilogue: distances, per-(sample, 128-code-block) min/argmin + exp sums.
    const float* x2 = norms;          // X2_OFF
    const float* c2 = norms + NS;     // C2_OFF
    int kg[8];
    #pragma unroll
    for (int j = 0; j < 4; ++j) { kg[j] = cBase + tc * 4 + j; kg[4 + j] = cBase + 64 + tc * 4 + j; }
    float c2v[8];
    #pragma unroll
    for (int j = 0; j < 8; ++j) c2v[j] = c2[kg[j]];

    #pragma unroll
    for (int i = 0; i < 8; ++i) {
        int s = sBase + tr * 8 + i;
        float xs = x2[s];
        float dj[8];
        float m = 3.4e38f; float mif = 0.f;
        #pragma unroll
        for (int j = 0; j < 8; ++j) {
            float dval = (xs - 2.0f * acc[i][j]) + c2v[j];
            dj[j] = dval;
            if (dval < m) { m = dval; mif = (float)kg[j]; }   // kg ascending -> first min
        }
        // reduce min+argmin across the 16 lanes sharing these samples
        #pragma unroll
        for (int off = 1; off < 16; off <<= 1) {
            float om  = __shfl_xor(m, off);
            float omi = __shfl_xor(mif, off);
            if (om < m || (om == m && omi < mif)) { m = om; mif = omi; }
        }
        float Z1 = 0.f, Zd = 0.f;
        #pragma unroll
        for (int j = 0; j < 8; ++j) {
            float e = __expf((m - dj[j]) * INV_T);   // <= 1, underflows to 0 far away
            Z1 += e;
            Zd += e * (dj[j] - m);
        }
        #pragma unroll
        for (int off = 1; off < 16; off <<= 1) {
            Z1 += __shfl_xor(Z1, off);
            Zd += __shfl_xor(Zd, off);
        }
        if (tc == 0) {
            float4 o; o.x = m; o.y = mif; o.z = Z1; o.w = Zd;
            *reinterpret_cast<float4*>(&summ[((size_t)s * NBLK + bx) * 4]) = o;
        }
    }
}

// -------------------------------------------------- per-sample reduction ----
__global__ __launch_bounds__(256) void vq_reduce(const float* __restrict__ summ,
                                                 float* __restrict__ hist,
                                                 float* __restrict__ scal,
                                                 int* __restrict__ idx_out,
                                                 float* __restrict__ out_idx_f) {
    int n = blockIdx.x * 256 + threadIdx.x;
    float4 sv[NBLK];
    #pragma unroll
    for (int j = 0; j < NBLK; ++j)
        sv[j] = *reinterpret_cast<const float4*>(&summ[((size_t)n * NBLK + j) * 4]);

    float m = 3.4e38f, mif = 0.f;
    #pragma unroll
    for (int j = 0; j < NBLK; ++j)
        if (sv[j].x < m) { m = sv[j].x; mif = sv[j].y; }   // ascending j -> first min

    float Z = 0.f, E = 0.f;
    #pragma unroll
    for (int j = 0; j < NBLK; ++j) {
        float a = __expf((m - sv[j].x) * INV_T);
        Z += a * sv[j].z;
        E += a * (sv[j].w + (sv[j].x - m) * sv[j].z);
    }
    // sample entropy: -sum p log p = E/(T*Z) + log Z
    float sent = E * INV_T / Z + logf(Z);

    #pragma unroll
    for (int j = 0; j < NBLK; ++j) {
        float a = __expf((m - sv[j].x) * INV_T);
        float mass = a * sv[j].z / Z;
        if (mass != 0.f) atomicAdd(&hist[(int)sv[j].y], mass);
    }

    int idx = (int)mif;
    idx_out[n]   = idx;
    out_idx_f[n] = mif;

    // accumulate sum(d_min) and sum(sample_entropy)
    float sm = m, ss = sent;
    #pragma unroll
    for (int off = 32; off; off >>= 1) { sm += __shfl_xor(sm, off); ss += __shfl_xor(ss, off); }
    if ((threadIdx.x & 63) == 0) { atomicAdd(&scal[0], sm); atomicAdd(&scal[1], ss); }
}

// ---------------------------------------------------------------- gather ----
__global__ __launch_bounds__(256) void vq_gather(const float* __restrict__ cb,
                                                 const int* __restrict__ idx,
                                                 float* __restrict__ outq) {
    int g  = blockIdx.x * 256 + threadIdx.x;   // < 32768*64
    int n  = g >> 6;
    int dv = g & 63;
    int k  = idx[n];
    const float4* cb4 = reinterpret_cast<const float4*>(cb);
    reinterpret_cast<float4*>(outq)[(size_t)n * 64 + dv] = cb4[(size_t)k * 64 + dv];
}

// -------------------------------------------------------------- finalize ----
__global__ __launch_bounds__(256) void vq_finalize(const float* __restrict__ hist,
                                                   const float* __restrict__ scal,
                                                   float* __restrict__ loss_out) {
    float local = 0.f;
    for (int k = threadIdx.x; k < KC; k += 256) {
        float p = hist[k] * (1.0f / (float)NS);
        local += -p * logf(p + 1e-5f);
    }
    __shared__ float red[4];
    #pragma unroll
    for (int off = 32; off; off >>= 1) local += __shfl_xor(local, off);
    int wave = threadIdx.x >> 6, lane = threadIdx.x & 63;
    if (lane == 0) red[wave] = local;
    __syncthreads();
    if (threadIdx.x == 0) {
        float avg_ent = red[0] + red[1] + red[2] + red[3];
        float sent    = scal[1] * (1.0f / (float)NS);
        float latent  = 1.25f * scal[0] / 8388608.0f;   // (0.25 + 1.0) * mean((q-x)^2)
        loss_out[0] = latent + 0.1f * (sent - avg_ent);
    }
}

extern "C" void kernel_launch(void* const* d_in, const int* in_sizes, int n_in,
                              void* d_out, int out_size, void* d_ws, size_t ws_size,
                              hipStream_t stream) {
    const float* x  = (const float*)d_in[0];
    const float* cb = (const float*)d_in[1];
    float* out = (float*)d_out;
    float* ws  = (float*)d_ws;

    // zero histogram + scalar accumulators
    hipMemsetAsync(ws + HIST_OFF, 0, (KC + 8) * sizeof(float), stream);

    vq_norms<<<(NS + KC) / 4, 256, 0, stream>>>(x, cb, ws + X2_OFF);
    vq_dist<<<dim3(NBLK, NS / 128), 256, 0, stream>>>(x, cb, ws + X2_OFF, ws + SUMM_OFF);
    vq_reduce<<<NS / 256, 256, 0, stream>>>(ws + SUMM_OFF, ws + HIST_OFF, ws + SCAL_OFF,
                                            (int*)(ws + IDXI_OFF), out + 8388609);
    vq_gather<<<(NS * 64) / 256, 256, 0, stream>>>(cb, (const int*)(ws + IDXI_OFF), out);
    vq_finalize<<<1, 256, 0, stream>>>(ws + HIST_OFF, ws + SCAL_OFF, out + 8388608);
}

// Round 2
// 147.728 us; speedup vs baseline: 1.8683x; 1.8683x over previous
//
#include <hip/hip_runtime.h>
#include <math.h>

typedef unsigned short u16;
typedef float    f32x4  __attribute__((ext_vector_type(4)));
typedef __bf16   bf16x8 __attribute__((ext_vector_type(8)));

#define NS    32768
#define DIMV  256
#define KC    1024
#define INV_T 100.0f
#define TAU   2.0f

// ws layout (float offsets)
#define X2_OFF   0
#define C2_OFF   NS                       // 32768
#define SUMM_OFF (NS + KC)                // 33792: [n][16 halfblocks] float4
#define SUMM_SZ  (NS * 16 * 4)            // 2,097,152 floats
#define HIST_OFF (SUMM_OFF + SUMM_SZ)
#define PD_OFF   (HIST_OFF + KC)
#define PS_OFF   (PD_OFF + 8192)
#define IDX_OFF  (PS_OFF + 8192)

__device__ __forceinline__ u16 f2bf(float f) {
    unsigned u = __float_as_uint(f);
    return (u16)((u + 0x7FFFu + ((u >> 16) & 1u)) >> 16);
}

__device__ __forceinline__ void gload_lds16(const void* g, void* l) {
    __builtin_amdgcn_global_load_lds((const __attribute__((address_space(1))) void*)g,
                                     (__attribute__((address_space(3))) void*)l, 16, 0, 0);
}

// ------------------------------------------- convert to bf16 + norms ----
__global__ __launch_bounds__(256) void vq_cvt_norms(const float* __restrict__ x,
                                                    const float* __restrict__ cb,
                                                    u16* __restrict__ xb,
                                                    u16* __restrict__ cbb,
                                                    float* __restrict__ norms) {
    int w = threadIdx.x >> 6, lane = threadIdx.x & 63;
    int row = blockIdx.x * 4 + w;                      // 0 .. 33791
    bool isx = row < NS;
    const float* src = isx ? x + (size_t)row * DIMV : cb + (size_t)(row - NS) * DIMV;
    float4 v = reinterpret_cast<const float4*>(src)[lane];
    float s = v.x * v.x + v.y * v.y + v.z * v.z + v.w * v.w;
    #pragma unroll
    for (int off = 32; off; off >>= 1) s += __shfl_xor(s, off);
    if (lane == 0) norms[row] = s;
    ushort4 o; o.x = f2bf(v.x); o.y = f2bf(v.y); o.z = f2bf(v.z); o.w = f2bf(v.w);
    u16* dst = isx ? xb + (size_t)row * DIMV : cbb + (size_t)(row - NS) * DIMV;
    reinterpret_cast<ushort4*>(dst)[lane] = o;
}

// ------------------------------------- bf16 MFMA distance + summaries ----
// grid (8 code-tiles, 256 sample-tiles), 256 threads = 4 waves (2x2 of 64x64).
__global__ __launch_bounds__(256) void vq_dist_mfma(const u16* __restrict__ xb,
                                                    const u16* __restrict__ cbb,
                                                    const float* __restrict__ norms,
                                                    float4* __restrict__ summ) {
    __shared__ __align__(16) u16 As[128 * 32];
    __shared__ __align__(16) u16 Bs[128 * 32];

    const int t = threadIdx.x;
    const int bx = blockIdx.x, by = blockIdx.y;
    const int sBase = by * 128, cBase = bx * 128;
    const int w = t >> 6, lane = t & 63;
    const int wr = w >> 1, wc = w & 1;
    const int lo16 = lane & 15, hi = lane >> 4;

    f32x4 acc[4][4];
    #pragma unroll
    for (int m = 0; m < 4; ++m)
        #pragma unroll
        for (int n = 0; n < 4; ++n) acc[m][n] = (f32x4)0.f;

    for (int kc = 0; kc < DIMV; kc += 32) {
        __syncthreads();
        #pragma unroll
        for (int q = 0; q < 2; ++q) {
            int c0 = (w * 2 + q) * 64;         // wave-uniform chunk base
            int c  = c0 + lane;
            int row = c >> 2, koff = (c & 3) * 8;
            gload_lds16(xb  + (size_t)(sBase + row) * DIMV + kc + koff, &As[c0 * 8]);
            gload_lds16(cbb + (size_t)(cBase + row) * DIMV + kc + koff, &Bs[c0 * 8]);
        }
        __syncthreads();
        bf16x8 af[4], bf[4];
        #pragma unroll
        for (int m = 0; m < 4; ++m)
            af[m] = *reinterpret_cast<const bf16x8*>(&As[(wr * 64 + m * 16 + lo16) * 32 + hi * 8]);
        #pragma unroll
        for (int n = 0; n < 4; ++n)
            bf[n] = *reinterpret_cast<const bf16x8*>(&Bs[(wc * 64 + n * 16 + lo16) * 32 + hi * 8]);
        #pragma unroll
        for (int m = 0; m < 4; ++m)
            #pragma unroll
            for (int n = 0; n < 4; ++n)
                acc[m][n] = __builtin_amdgcn_mfma_f32_16x16x32_bf16(af[m], bf[n], acc[m][n], 0, 0, 0);
    }

    // Epilogue: d = x2 - 2*acc + c2; per-row (sample) x 64-code half-block:
    // min + mask of codes within TAU of the half-block min.
    const float* x2 = norms;
    const float* c2 = norms + NS;
    float c2v[4];
    #pragma unroll
    for (int n = 0; n < 4; ++n) c2v[n] = c2[cBase + wc * 64 + n * 16 + lo16];
    const int hb = bx * 2 + wc;

    #pragma unroll
    for (int m = 0; m < 4; ++m) {
        #pragma unroll
        for (int r = 0; r < 4; ++r) {
            const int R = sBase + wr * 64 + m * 16 + hi * 4 + r;
            const float x2r = x2[R];
            float d[4];
            #pragma unroll
            for (int n = 0; n < 4; ++n)
                d[n] = (x2r - 2.0f * acc[m][n][r]) + c2v[n];
            float bm = d[0]; int bc = lo16;
            #pragma unroll
            for (int n = 1; n < 4; ++n)
                if (d[n] < bm) { bm = d[n]; bc = n * 16 + lo16; }
            #pragma unroll
            for (int off = 1; off < 16; off <<= 1) {
                float om = __shfl_xor(bm, off);
                int   oc = __shfl_xor(bc, off);
                if (om < bm || (om == bm && oc < bc)) { bm = om; bc = oc; }
            }
            const float thr = bm + TAU;
            unsigned long long mk = 0ull;
            #pragma unroll
            for (int n = 0; n < 4; ++n) {
                unsigned long long b = __ballot(d[n] < thr);
                mk |= ((b >> (hi * 16)) & 0xFFFFull) << (n * 16);
            }
            if (lo16 == 0) {
                float4 o;
                o.x = bm;
                o.y = (float)(cBase + wc * 64 + bc);
                o.z = __uint_as_float((unsigned)(mk & 0xFFFFFFFFull));
                o.w = __uint_as_float((unsigned)(mk >> 32));
                summ[(size_t)R * 16 + hb] = o;
            }
        }
    }
}

// ------------------------------------------ exact fp32 refine per sample ----
__global__ __launch_bounds__(256) void vq_refine(const float* __restrict__ x,
                                                 const float* __restrict__ cb,
                                                 const float* __restrict__ norms,
                                                 const float4* __restrict__ summ,
                                                 float* __restrict__ hist,
                                                 float* __restrict__ pd,
                                                 float* __restrict__ ps,
                                                 int* __restrict__ idx_out,
                                                 float* __restrict__ out_idx_f) {
    const int wid = threadIdx.x >> 6, lane = threadIdx.x & 63;
    const int s = blockIdx.x * 4 + wid;
    const float4 xv = reinterpret_cast<const float4*>(x)[(size_t)s * 64 + lane];
    const float x2s = norms[s];

    float gm = 3.4e38f;
    for (int hb = 0; hb < 16; ++hb) gm = fminf(gm, summ[(size_t)s * 16 + hb].x);
    const float lim = gm + TAU;

    float m = 0.f, S1 = 0.f, S2 = 0.f; int bk = 0;
    for (int hb = 0; hb < 16; ++hb) {
        float4 sm = summ[(size_t)s * 16 + hb];
        if (sm.x > lim) continue;
        unsigned long long mk =
            ((unsigned long long)__float_as_uint(sm.w) << 32) | __float_as_uint(sm.z);
        while (mk) {
            int b = __ffsll(mk) - 1; mk &= mk - 1;
            int k = hb * 64 + b;
            float4 cv = reinterpret_cast<const float4*>(cb)[(size_t)k * 64 + lane];
            float r = xv.x * cv.x + xv.y * cv.y + xv.z * cv.z + xv.w * cv.w;
            #pragma unroll
            for (int off = 32; off; off >>= 1) r += __shfl_xor(r, off);
            float dk = (x2s - 2.0f * r) + norms[NS + k];
            if (S1 == 0.f)      { m = dk; S1 = 1.f; S2 = 0.f; bk = k; }
            else if (dk < m)    { float f = __expf((dk - m) * INV_T);
                                  S2 = f * (S2 + (m - dk) * S1);
                                  S1 = S1 * f + 1.f;
                                  m = dk; bk = k; }
            else                { float e = __expf((m - dk) * INV_T);
                                  S1 += e; S2 += e * (dk - m); }
        }
    }
    float sent = S2 * INV_T / S1 + logf(S1);

    // histogram pass (recompute candidate distances; lane 0 atomics)
    for (int hb = 0; hb < 16; ++hb) {
        float4 sm = summ[(size_t)s * 16 + hb];
        if (sm.x > lim) continue;
        unsigned long long mk =
            ((unsigned long long)__float_as_uint(sm.w) << 32) | __float_as_uint(sm.z);
        while (mk) {
            int b = __ffsll(mk) - 1; mk &= mk - 1;
            int k = hb * 64 + b;
            float4 cv = reinterpret_cast<const float4*>(cb)[(size_t)k * 64 + lane];
            float r = xv.x * cv.x + xv.y * cv.y + xv.z * cv.z + xv.w * cv.w;
            #pragma unroll
            for (int off = 32; off; off >>= 1) r += __shfl_xor(r, off);
            float dk = (x2s - 2.0f * r) + norms[NS + k];
            if (lane == 0) atomicAdd(&hist[k], __expf((m - dk) * INV_T) / S1);
        }
    }

    if (lane == 0) { idx_out[s] = bk; out_idx_f[s] = (float)bk; }

    __shared__ float rd[4], rs[4];
    if (lane == 0) { rd[wid] = m; rs[wid] = sent; }
    __syncthreads();
    if (threadIdx.x == 0) {
        pd[blockIdx.x] = rd[0] + rd[1] + rd[2] + rd[3];
        ps[blockIdx.x] = rs[0] + rs[1] + rs[2] + rs[3];
    }
}

// ---------------------------------------------------------------- gather ----
__global__ __launch_bounds__(256) void vq_gather(const float* __restrict__ cb,
                                                 const int* __restrict__ idx,
                                                 float* __restrict__ outq) {
    int g  = blockIdx.x * 256 + threadIdx.x;
    int n  = g >> 6;
    int dv = g & 63;
    int k  = idx[n];
    reinterpret_cast<float4*>(outq)[(size_t)n * 64 + dv] =
        reinterpret_cast<const float4*>(cb)[(size_t)k * 64 + dv];
}

// -------------------------------------------------------------- finalize ----
__global__ __launch_bounds__(256) void vq_finalize(const float* __restrict__ hist,
                                                   const float* __restrict__ pd,
                                                   const float* __restrict__ ps,
                                                   float* __restrict__ loss_out) {
    float ae = 0.f, sd = 0.f, se = 0.f;
    for (int k = threadIdx.x; k < KC; k += 256) {
        float p = hist[k] * (1.0f / (float)NS);
        ae += -p * logf(p + 1e-5f);
    }
    for (int b = threadIdx.x; b < 8192; b += 256) { sd += pd[b]; se += ps[b]; }
    #pragma unroll
    for (int off = 32; off; off >>= 1) {
        ae += __shfl_xor(ae, off); sd += __shfl_xor(sd, off); se += __shfl_xor(se, off);
    }
    __shared__ float r[3][4];
    int wid = threadIdx.x >> 6, lane = threadIdx.x & 63;
    if (lane == 0) { r[0][wid] = ae; r[1][wid] = sd; r[2][wid] = se; }
    __syncthreads();
    if (threadIdx.x == 0) {
        float AE = r[0][0] + r[0][1] + r[0][2] + r[0][3];
        float SD = r[1][0] + r[1][1] + r[1][2] + r[1][3];
        float SE = r[2][0] + r[2][1] + r[2][2] + r[2][3];
        float latent = 1.25f * SD / 8388608.0f;
        loss_out[0] = latent + 0.1f * (SE * (1.0f / (float)NS) - AE);
    }
}

extern "C" void kernel_launch(void* const* d_in, const int* in_sizes, int n_in,
                              void* d_out, int out_size, void* d_ws, size_t ws_size,
                              hipStream_t stream) {
    const float* x  = (const float*)d_in[0];
    const float* cb = (const float*)d_in[1];
    float* out = (float*)d_out;
    float* ws  = (float*)d_ws;

    // bf16 scratch lives in the quantized-output region (overwritten by gather later)
    u16* xb  = (u16*)d_out;                       // 16 MB
    u16* cbb = (u16*)(out + 4194304);             // 0.5 MB

    hipMemsetAsync(ws + HIST_OFF, 0, KC * sizeof(float), stream);

    vq_cvt_norms<<<(NS + KC) / 4, 256, 0, stream>>>(x, cb, xb, cbb, ws + X2_OFF);
    vq_dist_mfma<<<dim3(8, 256), 256, 0, stream>>>(xb, cbb, ws + X2_OFF,
                                                   (float4*)(ws + SUMM_OFF));
    vq_refine<<<NS / 4, 256, 0, stream>>>(x, cb, ws + X2_OFF,
                                          (const float4*)(ws + SUMM_OFF),
                                          ws + HIST_OFF, ws + PD_OFF, ws + PS_OFF,
                                          (int*)(ws + IDX_OFF), out + 8388609);
    vq_gather<<<(NS * 64) / 256, 256, 0, stream>>>(cb, (const int*)(ws + IDX_OFF), out);
    vq_finalize<<<1, 256, 0, stream>>>(ws + HIST_OFF, ws + PD_OFF, ws + PS_OFF,
                                       out + 8388608);
}

// Round 3
// 116.801 us; speedup vs baseline: 2.3630x; 1.2648x over previous
//
#include <hip/hip_runtime.h>
#include <math.h>

typedef unsigned short u16;
typedef unsigned long long u64;
typedef float    f32x4  __attribute__((ext_vector_type(4)));
typedef __bf16   bf16x8 __attribute__((ext_vector_type(8)));

#define NS    32768
#define DIMV  256
#define KC    1024
#define INV_T 100.0f
#define TAU   2.0f

// ws layout (float offsets)
#define X2_OFF   0
#define SUMM_OFF (NS + KC)                // [n][16 halfblocks] float4
#define SUMM_SZ  (NS * 16 * 4)
#define HIST_OFF (SUMM_OFF + SUMM_SZ)
#define PD_OFF   (HIST_OFF + KC)
#define PS_OFF   (PD_OFF + 8192)

// tiled bf16 scratch (lives in d_out, overwritten later):
// per tile: 8 ks-steps x 512 chunks x 8 u16; chunk c = sub*128 + row (sub = k/8 within 32-k slice)
#define TILE_U16 (8 * 512 * 8)

__device__ __forceinline__ u16 f2bf(float f) {
    unsigned u = __float_as_uint(f);
    return (u16)((u + 0x7FFFu + ((u >> 16) & 1u)) >> 16);
}

__device__ __forceinline__ void gload_lds16(const void* g, void* l) {
    __builtin_amdgcn_global_load_lds((const __attribute__((address_space(1))) void*)g,
                                     (__attribute__((address_space(3))) void*)l, 16, 0, 0);
}

// --------------------- convert to tiled bf16 + norms (LDS transpose) ----
__global__ __launch_bounds__(256) void vq_cvt_norms(const float* __restrict__ x,
                                                    const float* __restrict__ cb,
                                                    u16* __restrict__ xt,
                                                    u16* __restrict__ ct,
                                                    float* __restrict__ norms) {
    __shared__ float sb[128 * 36];        // 128 rows x 32 k, pad to 36
    const int t = blockIdx.x;             // 0..263 (256 x-tiles + 8 cb-tiles)
    const bool isx = t < 256;
    const float* src = isx ? x + (size_t)t * 128 * DIMV
                           : cb + (size_t)(t - 256) * 128 * DIMV;
    u16* dst = isx ? xt + (size_t)t * TILE_U16 : ct + (size_t)(t - 256) * TILE_U16;
    const int i = threadIdx.x;
    float nacc[4] = {0.f, 0.f, 0.f, 0.f};

    for (int ks = 0; ks < 8; ++ks) {
        __syncthreads();
        #pragma unroll
        for (int jj = 0; jj < 4; ++jj) {
            int f = jj * 256 + i;                 // float4 unit 0..1023
            int r = f >> 3, k4 = f & 7;
            float4 v = *reinterpret_cast<const float4*>(src + (size_t)r * DIMV + ks * 32 + k4 * 4);
            nacc[jj] += v.x * v.x + v.y * v.y + v.z * v.z + v.w * v.w;
            *reinterpret_cast<float4*>(&sb[r * 36 + k4 * 4]) = v;
        }
        __syncthreads();
        #pragma unroll
        for (int jj = 0; jj < 2; ++jj) {
            int c = jj * 256 + i;                 // chunk 0..511
            int sub = c >> 7, r = c & 127;
            const float* p = &sb[r * 36 + sub * 8];
            ushort4 o0, o1;
            o0.x = f2bf(p[0]); o0.y = f2bf(p[1]); o0.z = f2bf(p[2]); o0.w = f2bf(p[3]);
            o1.x = f2bf(p[4]); o1.y = f2bf(p[5]); o1.z = f2bf(p[6]); o1.w = f2bf(p[7]);
            ushort4* d = reinterpret_cast<ushort4*>(dst + ((size_t)ks * 512 + c) * 8);
            d[0] = o0; d[1] = o1;
        }
    }
    #pragma unroll
    for (int jj = 0; jj < 4; ++jj) {
        float s = nacc[jj];
        s += __shfl_xor(s, 1); s += __shfl_xor(s, 2); s += __shfl_xor(s, 4);
        if ((i & 7) == 0) {
            int r = jj * 32 + (i >> 3);
            int grow = isx ? t * 128 + r : NS + (t - 256) * 128 + r;
            norms[grow] = s;
        }
    }
}

// ------------- bf16 MFMA distance + summaries (2-phase dbuf pipeline) ----
__global__ __launch_bounds__(256, 2) void vq_dist_mfma(const u16* __restrict__ xt,
                                                       const u16* __restrict__ ct,
                                                       const float* __restrict__ norms,
                                                       float4* __restrict__ summ) {
    __shared__ __align__(16) u16 As[2][4096];   // [buf][chunk*8], chunk = sub*128 + row
    __shared__ __align__(16) u16 Bs[2][4096];

    // bijective XCD swizzle: XCD k owns sample-tiles k*32..k*32+31, code tiles inner
    const int id = blockIdx.x;
    const int xcd = id & 7, j = id >> 3;
    const int by = xcd * 32 + (j >> 3), bx = j & 7;
    const int sBase = by * 128, cBase = bx * 128;

    const int t = threadIdx.x;
    const int w = t >> 6, lane = t & 63;
    const int wr = w >> 1, wc = w & 1;
    const int lo16 = lane & 15, hi = lane >> 4;
    const int c0 = w * 128;

    const u16* aT = xt + (size_t)by * TILE_U16;
    const u16* bT = ct + (size_t)bx * TILE_U16;

    f32x4 acc[4][4];
    #pragma unroll
    for (int m = 0; m < 4; ++m)
        #pragma unroll
        for (int n = 0; n < 4; ++n) acc[m][n] = (f32x4)0.f;

    #define STAGE(buf, ks)                                                        \
        do {                                                                      \
            const size_t o_ = (size_t)(ks) * 512;                                 \
            gload_lds16(aT + (o_ + c0      + lane) * 8, &As[buf][(c0      ) * 8]);\
            gload_lds16(aT + (o_ + c0 + 64 + lane) * 8, &As[buf][(c0 + 64 ) * 8]);\
            gload_lds16(bT + (o_ + c0      + lane) * 8, &Bs[buf][(c0      ) * 8]);\
            gload_lds16(bT + (o_ + c0 + 64 + lane) * 8, &Bs[buf][(c0 + 64 ) * 8]);\
        } while (0)

    STAGE(0, 0);
    __syncthreads();

    for (int it = 0; it < 8; ++it) {
        const int cur = it & 1;
        if (it < 7) STAGE(cur ^ 1, it + 1);
        bf16x8 af[4], bfr[4];
        #pragma unroll
        for (int m = 0; m < 4; ++m)
            af[m] = *reinterpret_cast<const bf16x8*>(
                &As[cur][(hi * 128 + wr * 64 + m * 16 + lo16) * 8]);
        #pragma unroll
        for (int n = 0; n < 4; ++n)
            bfr[n] = *reinterpret_cast<const bf16x8*>(
                &Bs[cur][(hi * 128 + wc * 64 + n * 16 + lo16) * 8]);
        #pragma unroll
        for (int m = 0; m < 4; ++m)
            #pragma unroll
            for (int n = 0; n < 4; ++n)
                acc[m][n] = __builtin_amdgcn_mfma_f32_16x16x32_bf16(af[m], bfr[n], acc[m][n], 0, 0, 0);
        __syncthreads();
    }
    #undef STAGE

    // Epilogue: per (sample row, 64-code half-block): min/argmin + TAU-mask
    const float* x2 = norms;
    const float* c2 = norms + NS;
    float c2v[4];
    #pragma unroll
    for (int n = 0; n < 4; ++n) c2v[n] = c2[cBase + wc * 64 + n * 16 + lo16];
    const int hb = bx * 2 + wc;

    #pragma unroll
    for (int m = 0; m < 4; ++m) {
        #pragma unroll
        for (int r = 0; r < 4; ++r) {
            const int R = sBase + wr * 64 + m * 16 + hi * 4 + r;
            const float x2r = x2[R];
            float d[4];
            #pragma unroll
            for (int n = 0; n < 4; ++n)
                d[n] = (x2r - 2.0f * acc[m][n][r]) + c2v[n];
            float bm = d[0]; int bc = lo16;
            #pragma unroll
            for (int n = 1; n < 4; ++n)
                if (d[n] < bm) { bm = d[n]; bc = n * 16 + lo16; }
            #pragma unroll
            for (int off = 1; off < 16; off <<= 1) {
                float om = __shfl_xor(bm, off);
                int   oc = __shfl_xor(bc, off);
                if (om < bm || (om == bm && oc < bc)) { bm = om; bc = oc; }
            }
            const float thr = bm + TAU;
            u64 mk = 0ull;
            #pragma unroll
            for (int n = 0; n < 4; ++n) {
                u64 b = __ballot(d[n] < thr);
                mk |= ((b >> (hi * 16)) & 0xFFFFull) << (n * 16);
            }
            if (lo16 == 0) {
                float4 o;
                o.x = bm;
                o.y = (float)(cBase + wc * 64 + bc);
                o.z = __uint_as_float((unsigned)(mk & 0xFFFFFFFFull));
                o.w = __uint_as_float((unsigned)(mk >> 32));
                summ[(size_t)R * 16 + hb] = o;
            }
        }
    }
}

// ---------- exact fp32 refine, single-pass, fused gather + histogram ----
__global__ __launch_bounds__(256) void vq_refine(const float* __restrict__ x,
                                                 const float* __restrict__ cb,
                                                 const float* __restrict__ norms,
                                                 const float4* __restrict__ summ,
                                                 float* __restrict__ hist,
                                                 float* __restrict__ pd,
                                                 float* __restrict__ ps,
                                                 float* __restrict__ outq,
                                                 float* __restrict__ out_idx_f) {
    __shared__ int   cd_k[4][128];
    __shared__ float cd_d[4][128];
    __shared__ float rd[4], rs[4];

    const int wid = threadIdx.x >> 6, lane = threadIdx.x & 63;
    const int s = blockIdx.x * 4 + wid;
    const float4 xv = reinterpret_cast<const float4*>(x)[(size_t)s * 64 + lane];
    const float x2s = norms[s];

    // parallel min over the 16 half-block summaries
    float gm = summ[(size_t)s * 16 + (lane & 15)].x;
    #pragma unroll
    for (int off = 1; off < 16; off <<= 1) gm = fminf(gm, __shfl_xor(gm, off));
    const float lim = gm + TAU;

    float m = 3.4e38f, S1 = 0.f, S2 = 0.f;
    int bk = 0, cnt = 0;
    for (int hb = 0; hb < 16; ++hb) {
        float4 sm = summ[(size_t)s * 16 + hb];
        if (sm.x > lim) continue;
        u64 mk = ((u64)__float_as_uint(sm.w) << 32) | __float_as_uint(sm.z);
        while (mk) {
            int b = __ffsll(mk) - 1; mk &= mk - 1;
            int k = hb * 64 + b;
            float4 cv = reinterpret_cast<const float4*>(cb)[(size_t)k * 64 + lane];
            float r = xv.x * cv.x + xv.y * cv.y + xv.z * cv.z + xv.w * cv.w;
            #pragma unroll
            for (int off = 32; off; off >>= 1) r += __shfl_xor(r, off);
            float dk = (x2s - 2.0f * r) + norms[NS + k];
            if (lane == 0 && cnt < 128) { cd_k[wid][cnt] = k; cd_d[wid][cnt] = dk; }
            ++cnt;
            if (S1 == 0.f)    { m = dk; S1 = 1.f; S2 = 0.f; bk = k; }
            else if (dk < m)  { float f = __expf((dk - m) * INV_T);
                                S2 = f * (S2 + (m - dk) * S1);
                                S1 = S1 * f + 1.f; m = dk; bk = k; }
            else              { float e = __expf((m - dk) * INV_T);
                                S1 += e; S2 += e * (dk - m); }
        }
    }
    float sent = S2 * INV_T / S1 + logf(S1);
    if (lane == 0) { rd[wid] = m; rs[wid] = sent; }
    __syncthreads();

    // lane-parallel histogram update
    if (cnt > 128) cnt = 128;
    for (int c = lane; c < cnt; c += 64) {
        float dk = cd_d[wid][c]; int k = cd_k[wid][c];
        atomicAdd(&hist[k], __expf((m - dk) * INV_T) / S1);
    }

    // fused gather: quantized row = codebook[bk]
    reinterpret_cast<float4*>(outq)[(size_t)s * 64 + lane] =
        reinterpret_cast<const float4*>(cb)[(size_t)bk * 64 + lane];
    if (lane == 0) out_idx_f[s] = (float)bk;

    if (threadIdx.x == 0) {
        pd[blockIdx.x] = rd[0] + rd[1] + rd[2] + rd[3];
        ps[blockIdx.x] = rs[0] + rs[1] + rs[2] + rs[3];
    }
}

// -------------------------------------------------------------- finalize ----
__global__ __launch_bounds__(256) void vq_finalize(const float* __restrict__ hist,
                                                   const float* __restrict__ pd,
                                                   const float* __restrict__ ps,
                                                   float* __restrict__ loss_out) {
    float ae = 0.f, sd = 0.f, se = 0.f;
    for (int k = threadIdx.x; k < KC; k += 256) {
        float p = hist[k] * (1.0f / (float)NS);
        ae += -p * logf(p + 1e-5f);
    }
    for (int b = threadIdx.x; b < 8192; b += 256) { sd += pd[b]; se += ps[b]; }
    #pragma unroll
    for (int off = 32; off; off >>= 1) {
        ae += __shfl_xor(ae, off); sd += __shfl_xor(sd, off); se += __shfl_xor(se, off);
    }
    __shared__ float r[3][4];
    int wid = threadIdx.x >> 6, lane = threadIdx.x & 63;
    if (lane == 0) { r[0][wid] = ae; r[1][wid] = sd; r[2][wid] = se; }
    __syncthreads();
    if (threadIdx.x == 0) {
        float AE = r[0][0] + r[0][1] + r[0][2] + r[0][3];
        float SD = r[1][0] + r[1][1] + r[1][2] + r[1][3];
        float SE = r[2][0] + r[2][1] + r[2][2] + r[2][3];
        float latent = 1.25f * SD / 8388608.0f;
        loss_out[0] = latent + 0.1f * (SE * (1.0f / (float)NS) - AE);
    }
}

extern "C" void kernel_launch(void* const* d_in, const int* in_sizes, int n_in,
                              void* d_out, int out_size, void* d_ws, size_t ws_size,
                              hipStream_t stream) {
    const float* x  = (const float*)d_in[0];
    const float* cb = (const float*)d_in[1];
    float* out = (float*)d_out;
    float* ws  = (float*)d_ws;

    // tiled bf16 scratch in the quantized-output region (overwritten by refine)
    u16* xt = (u16*)d_out;                   // 16.8 MB
    u16* ct = (u16*)(out + 4194304);         // 0.5 MB

    hipMemsetAsync(ws + HIST_OFF, 0, KC * sizeof(float), stream);

    vq_cvt_norms<<<264, 256, 0, stream>>>(x, cb, xt, ct, ws + X2_OFF);
    vq_dist_mfma<<<2048, 256, 0, stream>>>(xt, ct, ws + X2_OFF,
                                           (float4*)(ws + SUMM_OFF));
    vq_refine<<<NS / 4, 256, 0, stream>>>(x, cb, ws + X2_OFF,
                                          (const float4*)(ws + SUMM_OFF),
                                          ws + HIST_OFF, ws + PD_OFF, ws + PS_OFF,
                                          out, out + 8388609);
    vq_finalize<<<1, 256, 0, stream>>>(ws + HIST_OFF, ws + PD_OFF, ws + PS_OFF,
                                       out + 8388608);
}

// Round 4
// 111.150 us; speedup vs baseline: 2.4831x; 1.0508x over previous
//
#include <hip/hip_runtime.h>
#include <math.h>

typedef unsigned short u16;
typedef unsigned long long u64;
typedef float    f32x4  __attribute__((ext_vector_type(4)));
typedef __bf16   bf16x8 __attribute__((ext_vector_type(8)));

#define NS    32768
#define KC    1024
#define INV_T 100.0f
#define TAU   2.0f

// ws layout (float offsets)
#define C2_OFF   0
#define SUMM_OFF 1024                      // [n][16 halfblocks] float4
#define SUMM_SZ  (NS * 16 * 4)
#define HIST_OFF (SUMM_OFF + SUMM_SZ)
#define PD_OFF   (HIST_OFF + KC)
#define PS_OFF   (PD_OFF + 8192)

// ct: tiled bf16 codebook, 8 tiles x 4096 chunks x 16B = 512 KB (lives in d_out,
// overwritten by refine's quantized output afterwards).
#define TILE_U16 32768

__device__ __forceinline__ void gload_lds16(const void* g, void* l) {
    __builtin_amdgcn_global_load_lds((const __attribute__((address_space(1))) void*)g,
                                     (__attribute__((address_space(3))) void*)l, 16, 0, 0);
}

// --------------- cb prep: exact c2 + tiled bf16 codebook (64 blocks) ----
__global__ __launch_bounds__(256) void vq_cbprep(const float* __restrict__ cb,
                                                 u16* __restrict__ ct,
                                                 float* __restrict__ c2) {
    const int b = blockIdx.x;        // 64 blocks: tile T = b>>3, part p = b&7
    const int T = b >> 3, p = b & 7;
    const int t = threadIdx.x, w = t >> 6, lane = t & 63;

    // c2 for 16 rows (exact fp32)
    #pragma unroll
    for (int i = 0; i < 4; ++i) {
        int g = T * 128 + p * 16 + i * 4 + w;
        float4 v = reinterpret_cast<const float4*>(cb)[(size_t)g * 64 + lane];
        float s = v.x * v.x + v.y * v.y + v.z * v.z + v.w * v.w;
        #pragma unroll
        for (int off = 32; off; off >>= 1) s += __shfl_xor(s, off);
        if (lane == 0) c2[g] = s;
    }

    // tiled bf16: 512 chunks of this tile; chunk c = ks*512 + sub*128 + row
    #pragma unroll
    for (int i = 0; i < 2; ++i) {
        int c = p * 512 + i * 256 + t;
        int ks = c >> 9, idx = c & 511, sub = idx >> 7, row = idx & 127;
        const float* src = cb + (size_t)(T * 128 + row) * 256 + ks * 32 + sub * 8;
        float4 a0 = *reinterpret_cast<const float4*>(src);
        float4 a1 = *reinterpret_cast<const float4*>(src + 4);
        bf16x8 v;
        v[0]=(__bf16)a0.x; v[1]=(__bf16)a0.y; v[2]=(__bf16)a0.z; v[3]=(__bf16)a0.w;
        v[4]=(__bf16)a1.x; v[5]=(__bf16)a1.y; v[6]=(__bf16)a1.z; v[7]=(__bf16)a1.w;
        *reinterpret_cast<bf16x8*>(ct + (size_t)T * TILE_U16 + (size_t)c * 8) = v;
    }
}

// ------- distance MFMA: LDS-resident B, register-streamed fp32 A, no K barriers ----
// grid 1024 = 8 code-tiles x 128 sample-tiles (256 samples each). 4 waves; each
// wave owns 64 samples x 128 codes (acc[4][8]).
__global__ __launch_bounds__(256, 2) void vq_dist(const float* __restrict__ x,
                                                  const u16* __restrict__ ct,
                                                  const float* __restrict__ c2,
                                                  float4* __restrict__ summ) {
    __shared__ __align__(16) u16 Bs[TILE_U16];   // 64 KB

    // XCD-aware: xcd = id&7 owns by in [xcd*16, xcd*16+16); bx minor for A-reuse
    const int id = blockIdx.x;
    const int xcd = id & 7, r0 = id >> 3;
    const int by = xcd * 16 + (r0 >> 3), bx = r0 & 7;
    const int sBase = by * 256, cBase = bx * 128;

    const int t = threadIdx.x, w = t >> 6, lane = t & 63;
    const int lo16 = lane & 15, hi = lane >> 4;

    // stage whole B tile (once)
    const u16* bT = ct + (size_t)bx * TILE_U16;
    #pragma unroll
    for (int i = 0; i < 16; ++i) {
        int c0 = (i * 4 + w) * 64;
        gload_lds16(bT + (size_t)(c0 + lane) * 8, &Bs[c0 * 8]);
    }
    __syncthreads();

    const float* aw = x + (size_t)(sBase + w * 64) * 256;
    f32x4 acc[4][8];
    #pragma unroll
    for (int m = 0; m < 4; ++m)
        #pragma unroll
        for (int n = 0; n < 8; ++n) acc[m][n] = (f32x4)0.f;

    #pragma unroll
    for (int ks = 0; ks < 8; ++ks) {
        bf16x8 af[4];
        #pragma unroll
        for (int m = 0; m < 4; ++m) {
            const float* ap = aw + (size_t)(m * 16 + lo16) * 256 + ks * 32 + hi * 8;
            float4 a0 = *reinterpret_cast<const float4*>(ap);
            float4 a1 = *reinterpret_cast<const float4*>(ap + 4);
            bf16x8 v;
            v[0]=(__bf16)a0.x; v[1]=(__bf16)a0.y; v[2]=(__bf16)a0.z; v[3]=(__bf16)a0.w;
            v[4]=(__bf16)a1.x; v[5]=(__bf16)a1.y; v[6]=(__bf16)a1.z; v[7]=(__bf16)a1.w;
            af[m] = v;
        }
        bf16x8 bfr[8];
        #pragma unroll
        for (int n = 0; n < 8; ++n)
            bfr[n] = *reinterpret_cast<const bf16x8*>(
                &Bs[((ks * 512) + hi * 128 + n * 16 + lo16) * 8]);
        #pragma unroll
        for (int m = 0; m < 4; ++m)
            #pragma unroll
            for (int n = 0; n < 8; ++n)
                acc[m][n] = __builtin_amdgcn_mfma_f32_16x16x32_bf16(af[m], bfr[n], acc[m][n], 0, 0, 0);
    }

    // Epilogue: dd = c2 - 2*acc (x^2 cancels in all row-internal comparisons)
    float c2v[8];
    #pragma unroll
    for (int j = 0; j < 8; ++j) c2v[j] = c2[cBase + j * 16 + lo16];

    #pragma unroll
    for (int m = 0; m < 4; ++m) {
        #pragma unroll
        for (int r = 0; r < 4; ++r) {
            const int R = sBase + w * 64 + m * 16 + hi * 4 + r;
            float dd[8];
            #pragma unroll
            for (int j = 0; j < 8; ++j) dd[j] = fmaf(-2.0f, acc[m][j][r], c2v[j]);
            #pragma unroll
            for (int h = 0; h < 2; ++h) {
                float bm = fminf(fminf(dd[h*4], dd[h*4+1]), fminf(dd[h*4+2], dd[h*4+3]));
                #pragma unroll
                for (int off = 1; off < 16; off <<= 1) bm = fminf(bm, __shfl_xor(bm, off));
                const float thr = bm + TAU;
                u64 mk = 0ull;
                #pragma unroll
                for (int n = 0; n < 4; ++n) {
                    u64 b = __ballot(dd[h * 4 + n] < thr);
                    mk |= ((b >> (hi * 16)) & 0xFFFFull) << (n * 16);
                }
                if (lo16 == 0) {
                    float4 o;
                    o.x = bm;
                    o.y = 0.f;
                    o.z = __uint_as_float((unsigned)(mk & 0xFFFFFFFFull));
                    o.w = __uint_as_float((unsigned)(mk >> 32));
                    summ[(size_t)R * 16 + bx * 2 + h] = o;
                }
            }
        }
    }
}

// ---------- exact fp32 refine, single-pass, fused gather + histogram ----
__global__ __launch_bounds__(256) void vq_refine(const float* __restrict__ x,
                                                 const float* __restrict__ cb,
                                                 const float* __restrict__ c2,
                                                 const float4* __restrict__ summ,
                                                 float* __restrict__ hist,
                                                 float* __restrict__ pd,
                                                 float* __restrict__ ps,
                                                 float* __restrict__ outq,
                                                 float* __restrict__ out_idx_f) {
    __shared__ int   cd_k[4][128];
    __shared__ float cd_d[4][128];
    __shared__ float rd[4], rs[4];

    const int wid = threadIdx.x >> 6, lane = threadIdx.x & 63;
    const int s = blockIdx.x * 4 + wid;
    const float4 xv = reinterpret_cast<const float4*>(x)[(size_t)s * 64 + lane];

    // exact ||x_s||^2 (all lanes)
    float x2s = xv.x * xv.x + xv.y * xv.y + xv.z * xv.z + xv.w * xv.w;
    #pragma unroll
    for (int off = 32; off; off >>= 1) x2s += __shfl_xor(x2s, off);

    // parallel min over the 16 half-block summaries
    float gm = summ[(size_t)s * 16 + (lane & 15)].x;
    #pragma unroll
    for (int off = 1; off < 16; off <<= 1) gm = fminf(gm, __shfl_xor(gm, off));
    const float lim = gm + TAU;

    float m = 3.4e38f, S1 = 0.f, S2 = 0.f;
    int bk = 0, cnt = 0;
    for (int hb = 0; hb < 16; ++hb) {
        float4 sm = summ[(size_t)s * 16 + hb];
        if (sm.x > lim) continue;
        u64 mk = ((u64)__float_as_uint(sm.w) << 32) | __float_as_uint(sm.z);
        while (mk) {
            int b = __ffsll(mk) - 1; mk &= mk - 1;
            int k = hb * 64 + b;
            float4 cv = reinterpret_cast<const float4*>(cb)[(size_t)k * 64 + lane];
            float r = xv.x * cv.x + xv.y * cv.y + xv.z * cv.z + xv.w * cv.w;
            #pragma unroll
            for (int off = 32; off; off >>= 1) r += __shfl_xor(r, off);
            float dk = (x2s - 2.0f * r) + c2[k];
            if (lane == 0 && cnt < 128) { cd_k[wid][cnt] = k; cd_d[wid][cnt] = dk; }
            ++cnt;
            if (S1 == 0.f)    { m = dk; S1 = 1.f; S2 = 0.f; bk = k; }
            else if (dk < m)  { float f = __expf((dk - m) * INV_T);
                                S2 = f * (S2 + (m - dk) * S1);
                                S1 = S1 * f + 1.f; m = dk; bk = k; }
            else              { float e = __expf((m - dk) * INV_T);
                                S1 += e; S2 += e * (dk - m); }
        }
    }
    float sent = S2 * INV_T / S1 + logf(S1);
    if (lane == 0) { rd[wid] = m; rs[wid] = sent; }
    __syncthreads();

    // lane-parallel histogram update
    if (cnt > 128) cnt = 128;
    for (int c = lane; c < cnt; c += 64) {
        float dk = cd_d[wid][c]; int k = cd_k[wid][c];
        atomicAdd(&hist[k], __expf((m - dk) * INV_T) / S1);
    }

    // fused gather: quantized row = codebook[bk]
    reinterpret_cast<float4*>(outq)[(size_t)s * 64 + lane] =
        reinterpret_cast<const float4*>(cb)[(size_t)bk * 64 + lane];
    if (lane == 0) out_idx_f[s] = (float)bk;

    if (threadIdx.x == 0) {
        pd[blockIdx.x] = rd[0] + rd[1] + rd[2] + rd[3];
        ps[blockIdx.x] = rs[0] + rs[1] + rs[2] + rs[3];
    }
}

// -------------------------------------------------------------- finalize ----
__global__ __launch_bounds__(256) void vq_finalize(const float* __restrict__ hist,
                                                   const float* __restrict__ pd,
                                                   const float* __restrict__ ps,
                                                   float* __restrict__ loss_out) {
    float ae = 0.f, sd = 0.f, se = 0.f;
    for (int k = threadIdx.x; k < KC; k += 256) {
        float p = hist[k] * (1.0f / (float)NS);
        ae += -p * logf(p + 1e-5f);
    }
    for (int b = threadIdx.x; b < 8192; b += 256) { sd += pd[b]; se += ps[b]; }
    #pragma unroll
    for (int off = 32; off; off >>= 1) {
        ae += __shfl_xor(ae, off); sd += __shfl_xor(sd, off); se += __shfl_xor(se, off);
    }
    __shared__ float r[3][4];
    int wid = threadIdx.x >> 6, lane = threadIdx.x & 63;
    if (lane == 0) { r[0][wid] = ae; r[1][wid] = sd; r[2][wid] = se; }
    __syncthreads();
    if (threadIdx.x == 0) {
        float AE = r[0][0] + r[0][1] + r[0][2] + r[0][3];
        float SD = r[1][0] + r[1][1] + r[1][2] + r[1][3];
        float SE = r[2][0] + r[2][1] + r[2][2] + r[2][3];
        float latent = 1.25f * SD / 8388608.0f;
        loss_out[0] = latent + 0.1f * (SE * (1.0f / (float)NS) - AE);
    }
}

extern "C" void kernel_launch(void* const* d_in, const int* in_sizes, int n_in,
                              void* d_out, int out_size, void* d_ws, size_t ws_size,
                              hipStream_t stream) {
    const float* x  = (const float*)d_in[0];
    const float* cb = (const float*)d_in[1];
    float* out = (float*)d_out;
    float* ws  = (float*)d_ws;

    // tiled bf16 codebook in first 512 KB of d_out (overwritten by refine later)
    u16* ct = (u16*)d_out;

    hipMemsetAsync(ws + HIST_OFF, 0, KC * sizeof(float), stream);

    vq_cbprep<<<64, 256, 0, stream>>>(cb, ct, ws + C2_OFF);
    vq_dist<<<1024, 256, 0, stream>>>(x, ct, ws + C2_OFF, (float4*)(ws + SUMM_OFF));
    vq_refine<<<NS / 4, 256, 0, stream>>>(x, cb, ws + C2_OFF,
                                          (const float4*)(ws + SUMM_OFF),
                                          ws + HIST_OFF, ws + PD_OFF, ws + PS_OFF,
                                          out, out + 8388609);
    vq_finalize<<<1, 256, 0, stream>>>(ws + HIST_OFF, ws + PD_OFF, ws + PS_OFF,
                                       out + 8388608);
}